// Round 3
// baseline (2163.084 us; speedup 1.0000x reference)
//
#include <hip/hip_runtime.h>
#include <hip/hip_cooperative_groups.h>

namespace cg = cooperative_groups;

#define BTOT  2048   // B*t rows
#define HDIM  512
#define NSTEP 11
#define DIN   6
#define GCOLS 2048   // 4H gate columns

#define BK       32
#define NTHREADS 512

__device__ __forceinline__ float fsigmoid(float x) {
    return 1.0f / (1.0f + __expf(-x));
}
__device__ __forceinline__ float ftanh(float x) {
    // 1 - 2/(1+e^{2x}) : saturates correctly at +-inf
    return 1.0f - 2.0f / (1.0f + __expf(2.0f * x));
}

// Accumulate acc[8][4] += A[R0+rows, 0:512] * W[0:512, g*512 + U0 + tc] over K=512.
// A row-major [BTOT][HDIM]; W row-major [HDIM][GCOLS].
// LDS layouts:
//   ldsA[k][row]      k-major A tile; staging writes are 2-way-conflict-free
//                     (64 consecutive rows per wave write instr), inner reads
//                     are 32-way broadcast (2 distinct addrs per wave).
//   ldsW[k][unit][4]  gate-interleaved: one ds_read_b128 yields all 4 gates.
__device__ __forceinline__ void gemm_pass(
    float acc[8][4],
    const float* __restrict__ A,
    const float* __restrict__ W,
    int R0, int U0, int tid,
    float (*__restrict__ ldsA)[128], float (*__restrict__ ldsW)[32][4])
{
    const int tr = tid >> 5;          // 0..15 : 8-row group
    const int tc = tid & 31;          // 0..31 : unit within block

    // A staging: thread (ar, part) loads A[R0+ar][kc + part*8 .. +7]
    const int ar    = tid & 127;      // local row 0..127
    const int apart = tid >> 7;       // k sub-chunk 0..3
    const float* aptr = A + (size_t)(R0 + ar) * HDIM + apart * 8;

    // W staging: thread (wk, wu) loads W[kc+wk][g*512 + U0 + wu(+16)] for 4 gates
    const int wk = tid >> 4;          // 0..31 : k within chunk
    const int wu = tid & 15;          // 0..15 : unit
    const float* wptr = W + (size_t)wk * GCOLS + U0 + wu;

    // prefetch chunk 0 into registers
    float4 a0 = *(const float4*)(aptr);
    float4 a1 = *(const float4*)(aptr + 4);
    float wr[8];
    #pragma unroll
    for (int g = 0; g < 4; ++g) {
        wr[g]     = wptr[g * HDIM];
        wr[4 + g] = wptr[g * HDIM + 16];
    }

    for (int kc = 0; kc < HDIM; kc += BK) {
        __syncthreads();   // protect previous chunk's LDS reads
        // A: 8 scalar writes, banks = (ar)%32 with 64 consecutive ar/wave -> 2-way (free)
        ldsA[apart * 8 + 0][ar] = a0.x; ldsA[apart * 8 + 1][ar] = a0.y;
        ldsA[apart * 8 + 2][ar] = a0.z; ldsA[apart * 8 + 3][ar] = a0.w;
        ldsA[apart * 8 + 4][ar] = a1.x; ldsA[apart * 8 + 5][ar] = a1.y;
        ldsA[apart * 8 + 6][ar] = a1.z; ldsA[apart * 8 + 7][ar] = a1.w;
        // W: register transpose -> 2 aligned b128 writes, 16 consecutive granules/phase
        *(float4*)ldsW[wk][wu]      = make_float4(wr[0], wr[1], wr[2], wr[3]);
        *(float4*)ldsW[wk][wu + 16] = make_float4(wr[4], wr[5], wr[6], wr[7]);
        __syncthreads();
        // prefetch next chunk (latency hidden under the k-loop)
        if (kc + BK < HDIM) {
            a0 = *(const float4*)(aptr + kc + BK);
            a1 = *(const float4*)(aptr + kc + BK + 4);
            const float* wp2 = wptr + (size_t)(kc + BK) * GCOLS;
            #pragma unroll
            for (int g = 0; g < 4; ++g) {
                wr[g]     = wp2[g * HDIM];
                wr[4 + g] = wp2[g * HDIM + 16];
            }
        }
        #pragma unroll 8
        for (int k = 0; k < BK; ++k) {
            float aa[8];
            *(float4*)&aa[0] = *(const float4*)&ldsA[k][tr * 8];
            *(float4*)&aa[4] = *(const float4*)&ldsA[k][tr * 8 + 4];
            const float4 wv = *(const float4*)ldsW[k][tc];
            #pragma unroll
            for (int j = 0; j < 8; ++j) {
                acc[j][0] = fmaf(aa[j], wv.x, acc[j][0]);
                acc[j][1] = fmaf(aa[j], wv.y, acc[j][1]);
                acc[j][2] = fmaf(aa[j], wv.z, acc[j][2]);
                acc[j][3] = fmaf(aa[j], wv.w, acc[j][3]);
            }
        }
    }
}

__global__ __launch_bounds__(NTHREADS, 2)
void lstm2_kernel(const float* __restrict__ imus,
                  const float* __restrict__ k1, const float* __restrict__ r1,
                  const float* __restrict__ b1,
                  const float* __restrict__ k2, const float* __restrict__ r2,
                  const float* __restrict__ b2,
                  float* __restrict__ out, float* __restrict__ ws)
{
    __shared__ float ldsA[BK][128];      // 16 KB
    __shared__ float ldsW[BK][32][4];    // 16 KB, gate-interleaved

    const int wg = blockIdx.x;        // 0..255
    const int br = wg >> 4;           // row block 0..15
    const int bu = wg & 15;           // unit block 0..15
    const int R0 = br * 128;
    const int U0 = bu * 32;
    const int tid = threadIdx.x;
    const int tr = tid >> 5;
    const int tc = tid & 31;
    const int rloc = tr * 8;

    // h1 double-buffered in ws; h2 double-buffered across {ws, out}.
    // Parity: h2 writes go to h2buf[wb], wb = (t&1)^1; at t=10 wb=1 = out,
    // so the final h2 lands in d_out naturally. out is never read before
    // being fully written (t=0 writes it, t=1 reads it).
    float* h1buf[2] = { ws,                           ws + (size_t)BTOT * HDIM };
    float* h2buf[2] = { ws + 2 * (size_t)BTOT * HDIM, out };

    // constant fragments for this thread's 4 gate columns
    float bias1[4], bias2[4], k1f[DIN][4];
    #pragma unroll
    for (int g = 0; g < 4; ++g) {
        int col = g * HDIM + U0 + tc;
        bias1[g] = b1[col];
        bias2[g] = b2[col];
        #pragma unroll
        for (int d = 0; d < DIN; ++d) k1f[d][g] = k1[d * GCOLS + col];
    }

    float c1[8], c2[8];
    #pragma unroll
    for (int j = 0; j < 8; ++j) { c1[j] = 0.f; c2[j] = 0.f; }

    cg::grid_group grid = cg::this_grid();

    for (int t = 0; t < NSTEP; ++t) {
        const int rb = t & 1;
        const int wb = rb ^ 1;

        // ---------------- layer 1 : z1 = h1_old @ r1 + x_t @ k1 + b1 ----------------
        float acc[8][4];
        #pragma unroll
        for (int j = 0; j < 8; ++j)
            #pragma unroll
            for (int g = 0; g < 4; ++g) acc[j][g] = 0.f;

        if (t > 0) gemm_pass(acc, h1buf[rb], r1, R0, U0, tid, ldsA, ldsW);

        // x_t @ k1 (K=6) folded in; imus row stride 24 B, base 8 B-aligned
        #pragma unroll
        for (int j = 0; j < 8; ++j) {
            const float2* xp = (const float2*)(imus +
                ((size_t)(R0 + rloc + j) * NSTEP + t) * DIN);
            float2 p0 = xp[0], p1 = xp[1], p2 = xp[2];
            #pragma unroll
            for (int g = 0; g < 4; ++g) {
                float s = acc[j][g];
                s = fmaf(p0.x, k1f[0][g], s);
                s = fmaf(p0.y, k1f[1][g], s);
                s = fmaf(p1.x, k1f[2][g], s);
                s = fmaf(p1.y, k1f[3][g], s);
                s = fmaf(p2.x, k1f[4][g], s);
                s = fmaf(p2.y, k1f[5][g], s);
                acc[j][g] = s;
            }
        }

        #pragma unroll
        for (int j = 0; j < 8; ++j) {
            float zi = acc[j][0] + bias1[0];
            float zf = acc[j][1] + bias1[1];
            float zg = acc[j][2] + bias1[2];
            float zo = acc[j][3] + bias1[3];
            float c  = fsigmoid(zf) * c1[j] + fsigmoid(zi) * ftanh(zg);
            c1[j] = c;
            float h = fsigmoid(zo) * ftanh(c);
            h1buf[wb][(size_t)(R0 + rloc + j) * HDIM + U0 + tc] = h;
        }

        grid.sync();   // one grid sync per timestep is sufficient (hazard analysis in R0/R1 notes)

        // ---------------- layer 2 : z2 = h1_new @ k2 + h2_old @ r2 + b2 --------------
        #pragma unroll
        for (int j = 0; j < 8; ++j)
            #pragma unroll
            for (int g = 0; g < 4; ++g) acc[j][g] = 0.f;

        gemm_pass(acc, h1buf[wb], k2, R0, U0, tid, ldsA, ldsW);
        if (t > 0) gemm_pass(acc, h2buf[rb], r2, R0, U0, tid, ldsA, ldsW);

        #pragma unroll
        for (int j = 0; j < 8; ++j) {
            float zi = acc[j][0] + bias2[0];
            float zf = acc[j][1] + bias2[1];
            float zg = acc[j][2] + bias2[2];
            float zo = acc[j][3] + bias2[3];
            float c  = fsigmoid(zf) * c2[j] + fsigmoid(zi) * ftanh(zg);
            c2[j] = c;
            float h = fsigmoid(zo) * ftanh(c);
            h2buf[wb][(size_t)(R0 + rloc + j) * HDIM + U0 + tc] = h;
        }
        // no grid sync needed here: the t+1 L1 pass touches neither h2 nor
        // h1buf[wb]-as-read; the write/read pair is separated by t+1's grid.sync
    }
}

extern "C" void kernel_launch(void* const* d_in, const int* in_sizes, int n_in,
                              void* d_out, int out_size, void* d_ws, size_t ws_size,
                              hipStream_t stream)
{
    const float* imus = (const float*)d_in[0];
    const float* k1   = (const float*)d_in[1];
    const float* r1   = (const float*)d_in[2];
    const float* b1   = (const float*)d_in[3];
    const float* k2   = (const float*)d_in[4];
    const float* r2   = (const float*)d_in[5];
    const float* b2   = (const float*)d_in[6];
    float* out = (float*)d_out;
    float* ws  = (float*)d_ws;

    void* args[] = { &imus, &k1, &r1, &b1, &k2, &r2, &b2, &out, &ws };
    hipLaunchCooperativeKernel((const void*)lstm2_kernel, dim3(256), dim3(NTHREADS),
                               args, 0, stream);
}